// Round 1
// baseline (1403.071 us; speedup 1.0000x reference)
//
#include <hip/hip_runtime.h>
#include <cfloat>

#define NN 50000
#define DD 64
#define EE 1600000
#define NEG 0.2f

// -------- workspace layout (floats) --------
// h_gat : [0, NN*64)
// hp    : [NN*64, 2*NN*64)
// ssrc  : base + 0*NN
// sdst  : base + 1*NN
// m_lu  : base + 2*NN
// m_ld  : base + 3*NN
// d_lu  : base + 4*NN
// d_ld  : base + 5*NN   (base = 2*NN*64)

__device__ inline void atomicMaxF(float* addr, float v) {
    if (v >= 0.f) atomicMax((int*)addr, __float_as_int(v));
    else          atomicMin((unsigned int*)addr, __float_as_uint(v));
}

__device__ inline float leaky(float v) { return v >= 0.f ? v : NEG * v; }

// ---------------------------------------------------------------------------
// GEMM: h = feat@Wg + bg ; hp = feat@Wp + bp ; ssrc = h@a_src ; sdst = h@a_dst
// one wave per node; W matrices staged in LDS.
__global__ __launch_bounds__(256) void k_gemm(
    const float* __restrict__ feat, const float* __restrict__ Wg,
    const float* __restrict__ bg, const float* __restrict__ as_,
    const float* __restrict__ ad_, const float* __restrict__ Wp,
    const float* __restrict__ bp,
    float* __restrict__ h, float* __restrict__ hp,
    float* __restrict__ ssrc, float* __restrict__ sdst)
{
    __shared__ float sWg[64 * 64];
    __shared__ float sWp[64 * 64];
    __shared__ float sb[4 * 64];   // bg | bp | a_src | a_dst
    int t = threadIdx.x;
    for (int i = t; i < 4096; i += 256) { sWg[i] = Wg[i]; sWp[i] = Wp[i]; }
    if (t < 64)       sb[t]       = bg[t];
    else if (t < 128) sb[t]       = bp[t - 64];
    else if (t < 192) sb[t]       = as_[t - 128];
    else              sb[t]       = ad_[t - 192];
    __syncthreads();

    int lane = t & 63;
    int w    = t >> 6;                       // wave id in block (0..3)
    int nw   = (gridDim.x * blockDim.x) >> 6;
    for (int n = blockIdx.x * 4 + w; n < NN; n += nw) {
        float fv   = feat[n * 64 + lane];
        float accg = sb[lane];
        float accp = sb[64 + lane];
#pragma unroll
        for (int k = 0; k < 64; ++k) {
            float f = __shfl(fv, k, 64);
            accg = fmaf(f, sWg[k * 64 + lane], accg);
            accp = fmaf(f, sWp[k * 64 + lane], accp);
        }
        h [n * 64 + lane] = accg;
        hp[n * 64 + lane] = accp;
        float vs = accg * sb[128 + lane];
        float vd = accg * sb[192 + lane];
#pragma unroll
        for (int off = 32; off > 0; off >>= 1) {
            vs += __shfl_xor(vs, off, 64);
            vd += __shfl_xor(vd, off, 64);
        }
        if (lane == 0) { ssrc[n] = vs; sdst[n] = vd; }
    }
}

// ---------------------------------------------------------------------------
__global__ void k_init(float* __restrict__ out, float* __restrict__ m_lu,
                       float* __restrict__ m_ld, float* __restrict__ d_lu,
                       float* __restrict__ d_ld)
{
    int i = blockIdx.x * blockDim.x + threadIdx.x;
    if (i < NN * 64) out[i] = 0.f;
    if (i < NN) {
        m_lu[i] = -FLT_MAX; m_ld[i] = -FLT_MAX;
        d_lu[i] = 0.f;      d_ld[i] = 0.f;
    }
}

// ---------------------------------------------------------------------------
// segment-max of leaky(e) per dst, both edge lists fused (thread per edge).
__global__ void k_max(const int* __restrict__ lu, const int* __restrict__ ld,
                      const float* __restrict__ ssrc, const float* __restrict__ sdst,
                      float* __restrict__ m_lu, float* __restrict__ m_ld)
{
    int i = blockIdx.x * blockDim.x + threadIdx.x;
    if (i >= 2 * EE) return;
    const int* idx; float* m; int e;
    if (i < EE) { idx = lu; m = m_lu; e = i; }
    else        { idx = ld; m = m_ld; e = i - EE; }
    int s = idx[e], d = idx[EE + e];
    atomicMaxF(&m[d], leaky(ssrc[s] + sdst[d]));
}

// segment-sum of exp(e - m) per dst.
__global__ void k_sum(const int* __restrict__ lu, const int* __restrict__ ld,
                      const float* __restrict__ ssrc, const float* __restrict__ sdst,
                      const float* __restrict__ m_lu, const float* __restrict__ m_ld,
                      float* __restrict__ d_lu, float* __restrict__ d_ld)
{
    int i = blockIdx.x * blockDim.x + threadIdx.x;
    if (i >= 2 * EE) return;
    const int* idx; const float* m; float* den; int e;
    if (i < EE) { idx = lu; m = m_lu; den = d_lu; e = i; }
    else        { idx = ld; m = m_ld; den = d_ld; e = i - EE; }
    int s = idx[e], d = idx[EE + e];
    float v = leaky(ssrc[s] + sdst[d]);
    atomicAdd(&den[d], expf(v - m[d]));
}

// ---------------------------------------------------------------------------
// fused scatter: out[dst] += alpha * h[src]  (lu + ld)  and  out[r] += p * hp[c]
// one wave per edge-task; lane = channel.
__global__ __launch_bounds__(256) void k_scatter(
    const int* __restrict__ lu, const int* __restrict__ ld,
    const int* __restrict__ pi, const float* __restrict__ pv,
    const float* __restrict__ ssrc, const float* __restrict__ sdst,
    const float* __restrict__ m_lu, const float* __restrict__ m_ld,
    const float* __restrict__ d_lu, const float* __restrict__ d_ld,
    const float* __restrict__ h, const float* __restrict__ hp,
    float* __restrict__ out)
{
    int lane = threadIdx.x & 63;
    int wid  = (blockIdx.x * (blockDim.x >> 6)) + (threadIdx.x >> 6);
    int nw   = gridDim.x * (blockDim.x >> 6);
    for (int w = wid; w < 3 * EE; w += nw) {
        if (w < 2 * EE) {
            const int* idx; const float *m, *den; int e;
            if (w < EE) { idx = lu; m = m_lu; den = d_lu; e = w; }
            else        { idx = ld; m = m_ld; den = d_ld; e = w - EE; }
            int s = idx[e], d = idx[EE + e];
            float v     = leaky(ssrc[s] + sdst[d]);
            float alpha = expf(v - m[d]) / (den[d] + 1e-16f);
            atomicAdd(&out[d * 64 + lane], h[s * 64 + lane] * alpha);
        } else {
            int e = w - 2 * EE;
            int r = pi[e], c = pi[EE + e];
            atomicAdd(&out[r * 64 + lane], pv[e] * hp[c * 64 + lane]);
        }
    }
}

// ---------------------------------------------------------------------------
extern "C" void kernel_launch(void* const* d_in, const int* in_sizes, int n_in,
                              void* d_out, int out_size, void* d_ws, size_t ws_size,
                              hipStream_t stream)
{
    const float* feat = (const float*)d_in[0];
    const float* Wg   = (const float*)d_in[1];
    const float* bg   = (const float*)d_in[2];
    const float* as_  = (const float*)d_in[3];
    const float* ad_  = (const float*)d_in[4];
    const float* Wp   = (const float*)d_in[5];
    const float* bp   = (const float*)d_in[6];
    const float* pv   = (const float*)d_in[7];
    const int*   lu   = (const int*)d_in[8];
    const int*   ld   = (const int*)d_in[9];
    const int*   pi   = (const int*)d_in[10];
    float* out = (float*)d_out;

    float* ws   = (float*)d_ws;
    float* h    = ws;
    float* hp   = ws + (size_t)NN * 64;
    float* base = ws + 2 * (size_t)NN * 64;
    float* ssrc = base + 0 * NN;
    float* sdst = base + 1 * NN;
    float* m_lu = base + 2 * NN;
    float* m_ld = base + 3 * NN;
    float* d_lu = base + 4 * NN;
    float* d_ld = base + 5 * NN;

    hipLaunchKernelGGL(k_gemm, dim3(2048), dim3(256), 0, stream,
                       feat, Wg, bg, as_, ad_, Wp, bp, h, hp, ssrc, sdst);
    hipLaunchKernelGGL(k_init, dim3((NN * 64 + 255) / 256), dim3(256), 0, stream,
                       out, m_lu, m_ld, d_lu, d_ld);
    hipLaunchKernelGGL(k_max, dim3((2 * EE + 255) / 256), dim3(256), 0, stream,
                       lu, ld, ssrc, sdst, m_lu, m_ld);
    hipLaunchKernelGGL(k_sum, dim3((2 * EE + 255) / 256), dim3(256), 0, stream,
                       lu, ld, ssrc, sdst, m_lu, m_ld, d_lu, d_ld);
    hipLaunchKernelGGL(k_scatter, dim3(4096), dim3(256), 0, stream,
                       lu, ld, pi, pv, ssrc, sdst, m_lu, m_ld, d_lu, d_ld,
                       h, hp, out);
}

// Round 2
// 1107.956 us; speedup vs baseline: 1.2664x; 1.2664x over previous
//
#include <hip/hip_runtime.h>
#include <cfloat>

#define NN 50000
#define DD 64
#define EE 1600000
#define NEG 0.2f

__device__ inline float leaky(float v) { return v >= 0.f ? v : NEG * v; }

// ---------------------------------------------------------------------------
// GEMM: h = feat@Wg + bg ; hp = feat@Wp + bp ; ssrc = h@a_src ; sdst = h@a_dst
__global__ __launch_bounds__(256) void k_gemm(
    const float* __restrict__ feat, const float* __restrict__ Wg,
    const float* __restrict__ bg, const float* __restrict__ as_,
    const float* __restrict__ ad_, const float* __restrict__ Wp,
    const float* __restrict__ bp,
    float* __restrict__ h, float* __restrict__ hp,
    float* __restrict__ ssrc, float* __restrict__ sdst)
{
    __shared__ float sWg[64 * 64];
    __shared__ float sWp[64 * 64];
    __shared__ float sb[4 * 64];
    int t = threadIdx.x;
    for (int i = t; i < 4096; i += 256) { sWg[i] = Wg[i]; sWp[i] = Wp[i]; }
    if (t < 64)       sb[t] = bg[t];
    else if (t < 128) sb[t] = bp[t - 64];
    else if (t < 192) sb[t] = as_[t - 128];
    else              sb[t] = ad_[t - 192];
    __syncthreads();

    int lane = t & 63;
    int w    = t >> 6;
    int nw   = (gridDim.x * blockDim.x) >> 6;
    for (int n = blockIdx.x * 4 + w; n < NN; n += nw) {
        float fv   = feat[n * 64 + lane];
        float accg = sb[lane];
        float accp = sb[64 + lane];
#pragma unroll
        for (int k = 0; k < 64; ++k) {
            float f = __shfl(fv, k, 64);
            accg = fmaf(f, sWg[k * 64 + lane], accg);
            accp = fmaf(f, sWp[k * 64 + lane], accp);
        }
        h [n * 64 + lane] = accg;
        hp[n * 64 + lane] = accp;
        float vs = accg * sb[128 + lane];
        float vd = accg * sb[192 + lane];
#pragma unroll
        for (int off = 32; off > 0; off >>= 1) {
            vs += __shfl_xor(vs, off, 64);
            vd += __shfl_xor(vd, off, 64);
        }
        if (lane == 0) { ssrc[n] = vs; sdst[n] = vd; }
    }
}

// ---------------------------------------------------------------------------
__global__ void k_zero(int* __restrict__ cnt)
{
    int i = blockIdx.x * blockDim.x + threadIdx.x;
    if (i < 3 * NN) cnt[i] = 0;
}

// degree histogram per destination, all three lists.
// GAT lists: dst = idx[1] (second row). p list: dst = row = pi[0] (first row).
__global__ void k_hist(const int* __restrict__ lu, const int* __restrict__ ld,
                       const int* __restrict__ pi, int* __restrict__ cnt)
{
    int i = blockIdx.x * blockDim.x + threadIdx.x;
    if (i >= 3 * EE) return;
    if (i < EE)          atomicAdd(&cnt[lu[EE + i]], 1);
    else if (i < 2 * EE) atomicAdd(&cnt[NN + ld[EE + (i - EE)]], 1);
    else                 atomicAdd(&cnt[2 * NN + pi[i - 2 * EE]], 1);
}

// exclusive scan per list (blockIdx = list). Writes off[NN+1] and cursor copy.
__global__ __launch_bounds__(256) void k_scan(const int* __restrict__ cnt,
                                              int* __restrict__ off,
                                              int* __restrict__ cur)
{
    __shared__ int part[256];
    int list = blockIdx.x;
    const int* cb = cnt + list * NN;
    int* ob = off + list * (NN + 1);
    int* ub = cur + list * NN;
    int t = threadIdx.x;
    const int CH = (NN + 255) / 256;
    int lo = t * CH, hi = min(lo + CH, NN);
    int s = 0;
    for (int i = lo; i < hi; ++i) s += cb[i];
    part[t] = s;
    __syncthreads();
    for (int d = 1; d < 256; d <<= 1) {
        int v = 0;
        if (t >= d) v = part[t - d];
        __syncthreads();
        if (t >= d) part[t] += v;
        __syncthreads();
    }
    int run = (t == 0) ? 0 : part[t - 1];
    for (int i = lo; i < hi; ++i) {
        ob[i] = run; ub[i] = run;
        run += cb[i];
    }
    if (hi == NN) ob[NN] = run;
}

// scatter edges into CSR slots (payload: src for GAT; col+val for p).
__global__ void k_fill(const int* __restrict__ lu, const int* __restrict__ ld,
                       const int* __restrict__ pi, const float* __restrict__ pv,
                       int* __restrict__ cur,
                       int* __restrict__ s_lu, int* __restrict__ s_ld,
                       int* __restrict__ c_p, float* __restrict__ v_p)
{
    int i = blockIdx.x * blockDim.x + threadIdx.x;
    if (i >= 3 * EE) return;
    if (i < EE) {
        int e = i, s = lu[e], d = lu[EE + e];
        int pos = atomicAdd(&cur[d], 1);
        s_lu[pos] = s;
    } else if (i < 2 * EE) {
        int e = i - EE, s = ld[e], d = ld[EE + e];
        int pos = atomicAdd(&cur[NN + d], 1);
        s_ld[pos] = s;
    } else {
        int e = i - 2 * EE, r = pi[e], c = pi[EE + e];
        int pos = atomicAdd(&cur[2 * NN + r], 1);
        c_p[pos] = c; v_p[pos] = pv[e];
    }
}

// ---------------------------------------------------------------------------
// one wave per output node: in-register segment softmax + gather-accumulate.
__global__ __launch_bounds__(256) void k_gather(
    const int* __restrict__ off,
    const int* __restrict__ s_lu, const int* __restrict__ s_ld,
    const int* __restrict__ c_p, const float* __restrict__ v_p,
    const float* __restrict__ ssrc, const float* __restrict__ sdst,
    const float* __restrict__ h, const float* __restrict__ hp,
    float* __restrict__ out)
{
    int lane = threadIdx.x & 63;
    int wid  = blockIdx.x * (blockDim.x >> 6) + (threadIdx.x >> 6);
    int nw   = gridDim.x * (blockDim.x >> 6);
    for (int n = wid; n < NN; n += nw) {
        float acc = 0.f;
        float sd  = sdst[n];
        // --- two GAT lists ---
        for (int list = 0; list < 2; ++list) {
            const int* ss = list ? s_ld : s_lu;
            const int* ob = off + list * (NN + 1);
            int b = ob[n], e = ob[n + 1];
            if (e <= b) continue;
            // phase A: online max + denom, 64 edges per chunk
            float m = -FLT_MAX, den = 0.f;
            for (int cb = b; cb < e; cb += 64) {
                int j = cb + lane;
                float ev = -FLT_MAX;
                if (j < e) ev = leaky(ssrc[ss[j]] + sd);
                float cm = ev;
#pragma unroll
                for (int o = 32; o; o >>= 1) cm = fmaxf(cm, __shfl_xor(cm, o, 64));
                if (cm > m) { den *= __expf(m - cm); m = cm; }
                float ex = (j < e) ? __expf(ev - m) : 0.f;
#pragma unroll
                for (int o = 32; o; o >>= 1) ex += __shfl_xor(ex, o, 64);
                den += ex;
            }
            float inv = 1.f / (den + 1e-16f);
            // phase B: weighted row gather, shfl-broadcast per edge
            for (int cb = b; cb < e; cb += 64) {
                int j = cb + lane;
                int sl = 0; float wl = 0.f;
                if (j < e) { sl = ss[j]; wl = __expf(leaky(ssrc[sl] + sd) - m) * inv; }
                int cnt64 = min(64, e - cb);
                for (int k = 0; k < cnt64; ++k) {
                    int   sj = __shfl(sl, k, 64);
                    float wj = __shfl(wl, k, 64);
                    acc = fmaf(wj, h[sj * 64 + lane], acc);
                }
            }
        }
        // --- p list (plain weighted SpMM) ---
        {
            const int* ob = off + 2 * (NN + 1);
            int b = ob[n], e = ob[n + 1];
            for (int cb = b; cb < e; cb += 64) {
                int j = cb + lane;
                int cl = 0; float vl = 0.f;
                if (j < e) { cl = c_p[j]; vl = v_p[j]; }
                int cnt64 = min(64, e - cb);
                for (int k = 0; k < cnt64; ++k) {
                    int   cj = __shfl(cl, k, 64);
                    float vj = __shfl(vl, k, 64);
                    acc = fmaf(vj, hp[cj * 64 + lane], acc);
                }
            }
        }
        out[n * 64 + lane] = acc;
    }
}

// ---------------------------------------------------------------------------
extern "C" void kernel_launch(void* const* d_in, const int* in_sizes, int n_in,
                              void* d_out, int out_size, void* d_ws, size_t ws_size,
                              hipStream_t stream)
{
    const float* feat = (const float*)d_in[0];
    const float* Wg   = (const float*)d_in[1];
    const float* bg   = (const float*)d_in[2];
    const float* as_  = (const float*)d_in[3];
    const float* ad_  = (const float*)d_in[4];
    const float* Wp   = (const float*)d_in[5];
    const float* bp   = (const float*)d_in[6];
    const float* pv   = (const float*)d_in[7];
    const int*   lu   = (const int*)d_in[8];
    const int*   ld   = (const int*)d_in[9];
    const int*   pi   = (const int*)d_in[10];
    float* out = (float*)d_out;

    // workspace layout (4B units)
    float* ws   = (float*)d_ws;
    float* h    = ws;                               // NN*64
    float* hp   = h + (size_t)NN * 64;              // NN*64
    float* ssrc = hp + (size_t)NN * 64;             // NN
    float* sdst = ssrc + NN;                        // NN
    int*   cnt  = (int*)(sdst + NN);                // 3*NN
    int*   off  = cnt + 3 * NN;                     // 3*(NN+1)
    int*   cur  = off + 3 * (NN + 1);               // 3*NN
    int*   s_lu = cur + 3 * NN;                     // EE
    int*   s_ld = s_lu + EE;                        // EE
    int*   c_p  = s_ld + EE;                        // EE
    float* v_p  = (float*)(c_p + EE);               // EE

    hipLaunchKernelGGL(k_gemm, dim3(2048), dim3(256), 0, stream,
                       feat, Wg, bg, as_, ad_, Wp, bp, h, hp, ssrc, sdst);
    hipLaunchKernelGGL(k_zero, dim3((3 * NN + 255) / 256), dim3(256), 0, stream, cnt);
    hipLaunchKernelGGL(k_hist, dim3((3 * EE + 255) / 256), dim3(256), 0, stream,
                       lu, ld, pi, cnt);
    hipLaunchKernelGGL(k_scan, dim3(3), dim3(256), 0, stream, cnt, off, cur);
    hipLaunchKernelGGL(k_fill, dim3((3 * EE + 255) / 256), dim3(256), 0, stream,
                       lu, ld, pi, pv, cur, s_lu, s_ld, c_p, v_p);
    hipLaunchKernelGGL(k_gather, dim3(3125), dim3(256), 0, stream,
                       off, s_lu, s_ld, c_p, v_p, ssrc, sdst, h, hp, out);
}